// Round 1
// baseline (301.899 us; speedup 1.0000x reference)
//
#include <hip/hip_runtime.h>

#define N_PTS 65536
#define NSS 16
#define C 64

// ---------------- QKV: one wave per point, lane = output channel ----------------
__global__ __launch_bounds__(256) void qkv_kernel(
    const float* __restrict__ x,
    const float* __restrict__ Wq, const float* __restrict__ bq,
    const float* __restrict__ Wk, const float* __restrict__ bk,
    const float* __restrict__ Wv, const float* __restrict__ bv,
    float* __restrict__ xq, float* __restrict__ xk, float* __restrict__ xv) {
  const int lane = threadIdx.x & 63;
  const int n = (blockIdx.x * blockDim.x + threadIdx.x) >> 6;
  const float xr = x[n * C + lane];
  float q = bq[lane], k = bk[lane], v = bv[lane];
#pragma unroll 8
  for (int t = 0; t < C; ++t) {
    const float xb = __shfl(xr, t, 64);
    q = fmaf(xb, Wq[t * C + lane], q);
    k = fmaf(xb, Wk[t * C + lane], k);
    v = fmaf(xb, Wv[t * C + lane], v);
  }
  xq[n * C + lane] = q;
  xk[n * C + lane] = k;
  xv[n * C + lane] = v;
}

// ---------------- p_r moment reduction: 3 first moments + 6 second moments ----------------
__global__ __launch_bounds__(256) void stats_kernel(
    const float* __restrict__ p, const int* __restrict__ idx,
    float* __restrict__ stats) {
  const int tid = blockIdx.x * blockDim.x + threadIdx.x;
  const int stride = gridDim.x * blockDim.x;
  float s0 = 0, s1 = 0, s2 = 0, s00 = 0, s01 = 0, s02 = 0, s11 = 0, s12 = 0, s22 = 0;
  for (int t = tid; t < N_PTS * NSS; t += stride) {
    const int n = t >> 4;
    const int j = idx[t];
    const float dx = p[j * 3 + 0] - p[n * 3 + 0];
    const float dy = p[j * 3 + 1] - p[n * 3 + 1];
    const float dz = p[j * 3 + 2] - p[n * 3 + 2];
    s0 += dx; s1 += dy; s2 += dz;
    s00 += dx * dx; s01 += dx * dy; s02 += dx * dz;
    s11 += dy * dy; s12 += dy * dz; s22 += dz * dz;
  }
#pragma unroll
  for (int m = 1; m < 64; m <<= 1) {
    s0 += __shfl_xor(s0, m, 64);  s1 += __shfl_xor(s1, m, 64);  s2 += __shfl_xor(s2, m, 64);
    s00 += __shfl_xor(s00, m, 64); s01 += __shfl_xor(s01, m, 64); s02 += __shfl_xor(s02, m, 64);
    s11 += __shfl_xor(s11, m, 64); s12 += __shfl_xor(s12, m, 64); s22 += __shfl_xor(s22, m, 64);
  }
  __shared__ float part[4][9];
  const int wave = threadIdx.x >> 6, lane = threadIdx.x & 63;
  if (lane == 0) {
    part[wave][0] = s0;  part[wave][1] = s1;  part[wave][2] = s2;
    part[wave][3] = s00; part[wave][4] = s01; part[wave][5] = s02;
    part[wave][6] = s11; part[wave][7] = s12; part[wave][8] = s22;
  }
  __syncthreads();
  if (threadIdx.x < 9) {
    const float acc = part[0][threadIdx.x] + part[1][threadIdx.x] +
                      part[2][threadIdx.x] + part[3][threadIdx.x];
    atomicAdd(&stats[threadIdx.x], acc);
  }
}

// ---------------- fold BN(+gamma,beta) into effective Wp1/bp1 ----------------
__global__ void finalize_kernel(
    const float* __restrict__ stats,
    const float* __restrict__ Wp1, const float* __restrict__ bp1,
    const float* __restrict__ gamma, const float* __restrict__ beta,
    float* __restrict__ eff) {
  if (threadIdx.x != 0 || blockIdx.x != 0) return;
  const float invM = 1.0f / (float)(N_PTS * NSS);
  const float m0 = stats[0] * invM, m1 = stats[1] * invM, m2 = stats[2] * invM;
  float cov[3][3];
  cov[0][0] = stats[3] * invM - m0 * m0;
  cov[0][1] = cov[1][0] = stats[4] * invM - m0 * m1;
  cov[0][2] = cov[2][0] = stats[5] * invM - m0 * m2;
  cov[1][1] = stats[6] * invM - m1 * m1;
  cov[1][2] = cov[2][1] = stats[7] * invM - m1 * m2;
  cov[2][2] = stats[8] * invM - m2 * m2;
  const float mean[3] = {m0, m1, m2};
  for (int t = 0; t < 3; ++t) {
    const float w[3] = {Wp1[0 * 3 + t], Wp1[1 * 3 + t], Wp1[2 * 3 + t]};
    const float mh = w[0] * mean[0] + w[1] * mean[1] + w[2] * mean[2] + bp1[t];
    float var = 0.f;
    for (int d = 0; d < 3; ++d)
      for (int e = 0; e < 3; ++e) var += w[d] * w[e] * cov[d][e];
    const float scale = gamma[t] * rsqrtf(var + 1e-5f);
    eff[0 * 3 + t] = w[0] * scale;
    eff[1 * 3 + t] = w[1] * scale;
    eff[2 * 3 + t] = w[2] * scale;
    eff[9 + t] = (bp1[t] - mh) * scale + beta[t];
  }
}

// ---------------- main attention: one wave per point, lane = channel ----------------
__global__ __launch_bounds__(256) void attn_kernel(
    const float* __restrict__ p, const int* __restrict__ idx,
    const float* __restrict__ xq, const float* __restrict__ xk, const float* __restrict__ xv,
    const float* __restrict__ eff, const float* __restrict__ Wp2, const float* __restrict__ bp2,
    float* __restrict__ out) {
  const int lane = threadIdx.x & 63;
  const int n = (blockIdx.x * blockDim.x + threadIdx.x) >> 6;
  float w1e[9];
#pragma unroll
  for (int i = 0; i < 9; ++i) w1e[i] = eff[i];
  const float b1e0 = eff[9], b1e1 = eff[10], b1e2 = eff[11];
  const float wp20 = Wp2[0 * C + lane], wp21 = Wp2[1 * C + lane], wp22 = Wp2[2 * C + lane];
  const float b2 = bp2[lane];
  const float q = xq[n * C + lane];
  const float pnx = p[n * 3 + 0], pny = p[n * 3 + 1], pnz = p[n * 3 + 2];
  float attn[NSS], vv[NSS];
#pragma unroll
  for (int s = 0; s < NSS; ++s) {
    const int j = idx[n * NSS + s];
    const float kc = xk[j * C + lane];
    const float vc = xv[j * C + lane];
    const float dx = p[j * 3 + 0] - pnx;
    const float dy = p[j * 3 + 1] - pny;
    const float dz = p[j * 3 + 2] - pnz;
    const float h0 = fmaxf(fmaf(dx, w1e[0], fmaf(dy, w1e[3], fmaf(dz, w1e[6], b1e0))), 0.f);
    const float h1 = fmaxf(fmaf(dx, w1e[1], fmaf(dy, w1e[4], fmaf(dz, w1e[7], b1e1))), 0.f);
    const float h2 = fmaxf(fmaf(dx, w1e[2], fmaf(dy, w1e[5], fmaf(dz, w1e[8], b1e2))), 0.f);
    const float pe = fmaf(h0, wp20, fmaf(h1, wp21, fmaf(h2, wp22, b2)));
    float a = q * (kc + pe);
#pragma unroll
    for (int m = 1; m < 64; m <<= 1) a += __shfl_xor(a, m, 64);
    attn[s] = a * 0.125f;
    vv[s] = vc + pe;
  }
  float mx = attn[0];
#pragma unroll
  for (int s = 1; s < NSS; ++s) mx = fmaxf(mx, attn[s]);
  float den = 0.f, o = 0.f;
#pragma unroll
  for (int s = 0; s < NSS; ++s) {
    const float e = __expf(attn[s] - mx);
    den += e;
    o = fmaf(e, vv[s], o);
  }
  out[n * C + lane] = o / den;
}

extern "C" void kernel_launch(void* const* d_in, const int* in_sizes, int n_in,
                              void* d_out, int out_size, void* d_ws, size_t ws_size,
                              hipStream_t stream) {
  const float* p     = (const float*)d_in[0];
  const float* x     = (const float*)d_in[1];
  const int*   idx   = (const int*)d_in[2];
  const float* Wq    = (const float*)d_in[3];
  const float* bq    = (const float*)d_in[4];
  const float* Wk    = (const float*)d_in[5];
  const float* bk    = (const float*)d_in[6];
  const float* Wv    = (const float*)d_in[7];
  const float* bv    = (const float*)d_in[8];
  const float* Wp1   = (const float*)d_in[9];
  const float* bp1   = (const float*)d_in[10];
  const float* gamma = (const float*)d_in[11];
  const float* beta  = (const float*)d_in[12];
  const float* Wp2   = (const float*)d_in[13];
  const float* bp2   = (const float*)d_in[14];
  float* out = (float*)d_out;

  float* ws_f  = (float*)d_ws;
  float* stats = ws_f;        // 9 floats, zeroed below (ws is poisoned each call)
  float* eff   = ws_f + 16;   // 12 floats
  float* xq    = ws_f + 1024; // N*64 each
  float* xk    = xq + N_PTS * C;
  float* xv    = xk + N_PTS * C;

  hipMemsetAsync(stats, 0, 9 * sizeof(float), stream);
  qkv_kernel<<<N_PTS / 4, 256, 0, stream>>>(x, Wq, bq, Wk, bk, Wv, bv, xq, xk, xv);
  stats_kernel<<<1024, 256, 0, stream>>>(p, idx, stats);
  finalize_kernel<<<1, 64, 0, stream>>>(stats, Wp1, bp1, gamma, beta, eff);
  attn_kernel<<<N_PTS / 4, 256, 0, stream>>>(p, idx, xq, xk, xv, eff, Wp2, bp2, out);
}

// Round 2
// 225.248 us; speedup vs baseline: 1.3403x; 1.3403x over previous
//
#include <hip/hip_runtime.h>

#define N_PTS 65536
#define NSS 16
#define C 64

// ---------------- QKV: LDS-tiled fp32 GEMM, 64 points per block ----------------
// Outputs: xq[N][64], kv[N][128] (k row | v row interleaved)
__global__ __launch_bounds__(256, 2) void qkv_kernel(
    const float* __restrict__ x,
    const float* __restrict__ Wq, const float* __restrict__ bq,
    const float* __restrict__ Wk, const float* __restrict__ bk,
    const float* __restrict__ Wv, const float* __restrict__ bv,
    float* __restrict__ xq, float* __restrict__ kv) {
  __shared__ __align__(16) float ws[3][64][64];  // 48 KB
  __shared__ __align__(16) float xs[64][68];     // 17.4 KB, pitch 68 (16B-aligned, 2-way-max bank)
  const int t = threadIdx.x;
  const int p0 = blockIdx.x * 64;

  // stage W (3*1024 float4)
  for (int i = t; i < 3 * 1024; i += 256) {
    const int mat = i >> 10, off = i & 1023;
    const float4 v = ((const float4*)(mat == 0 ? Wq : (mat == 1 ? Wk : Wv)))[off];
    ((float4*)&ws[mat][0][0])[off] = v;
  }
  // stage x tile (64*16 float4)
  for (int i = t; i < 1024; i += 256) {
    const int p = i >> 4, c4 = (i & 15) << 2;
    const float4 v = ((const float4*)x)[(p0 + p) * 16 + (i & 15)];
    *(float4*)&xs[p][c4] = v;
  }
  __syncthreads();

  const int m = t & 15;        // channel group (4 channels)
  const int pb = (t >> 4) * 4; // 4 points
  float aq[4][4] = {}, ak[4][4] = {}, av[4][4] = {};
#pragma unroll 4
  for (int k = 0; k < 64; ++k) {
    const float xp0 = xs[pb + 0][k], xp1 = xs[pb + 1][k];
    const float xp2 = xs[pb + 2][k], xp3 = xs[pb + 3][k];
    const float4 wq = *(const float4*)&ws[0][k][m << 2];
    const float4 wk = *(const float4*)&ws[1][k][m << 2];
    const float4 wv = *(const float4*)&ws[2][k][m << 2];
    const float xp[4] = {xp0, xp1, xp2, xp3};
#pragma unroll
    for (int i = 0; i < 4; ++i) {
      aq[i][0] = fmaf(xp[i], wq.x, aq[i][0]); aq[i][1] = fmaf(xp[i], wq.y, aq[i][1]);
      aq[i][2] = fmaf(xp[i], wq.z, aq[i][2]); aq[i][3] = fmaf(xp[i], wq.w, aq[i][3]);
      ak[i][0] = fmaf(xp[i], wk.x, ak[i][0]); ak[i][1] = fmaf(xp[i], wk.y, ak[i][1]);
      ak[i][2] = fmaf(xp[i], wk.z, ak[i][2]); ak[i][3] = fmaf(xp[i], wk.w, ak[i][3]);
      av[i][0] = fmaf(xp[i], wv.x, av[i][0]); av[i][1] = fmaf(xp[i], wv.y, av[i][1]);
      av[i][2] = fmaf(xp[i], wv.z, av[i][2]); av[i][3] = fmaf(xp[i], wv.w, av[i][3]);
    }
  }
  const float4 bq4 = ((const float4*)bq)[m];
  const float4 bk4 = ((const float4*)bk)[m];
  const float4 bv4 = ((const float4*)bv)[m];
#pragma unroll
  for (int i = 0; i < 4; ++i) {
    const int p = p0 + pb + i;
    float4 oq = {aq[i][0] + bq4.x, aq[i][1] + bq4.y, aq[i][2] + bq4.z, aq[i][3] + bq4.w};
    float4 ok = {ak[i][0] + bk4.x, ak[i][1] + bk4.y, ak[i][2] + bk4.z, ak[i][3] + bk4.w};
    float4 ov = {av[i][0] + bv4.x, av[i][1] + bv4.y, av[i][2] + bv4.z, av[i][3] + bv4.w};
    ((float4*)xq)[p * 16 + m] = oq;
    ((float4*)kv)[p * 32 + m] = ok;
    ((float4*)kv)[p * 32 + 16 + m] = ov;
  }
}

// ---------------- p_r moment reduction ----------------
__global__ __launch_bounds__(256) void stats_kernel(
    const float* __restrict__ p, const int* __restrict__ idx,
    float* __restrict__ stats) {
  const int tid = blockIdx.x * blockDim.x + threadIdx.x;
  const int stride = gridDim.x * blockDim.x;
  float s0 = 0, s1 = 0, s2 = 0, s00 = 0, s01 = 0, s02 = 0, s11 = 0, s12 = 0, s22 = 0;
  for (int t = tid; t < N_PTS * NSS; t += stride) {
    const int n = t >> 4;
    const int j = idx[t];
    const float dx = p[j * 3 + 0] - p[n * 3 + 0];
    const float dy = p[j * 3 + 1] - p[n * 3 + 1];
    const float dz = p[j * 3 + 2] - p[n * 3 + 2];
    s0 += dx; s1 += dy; s2 += dz;
    s00 += dx * dx; s01 += dx * dy; s02 += dx * dz;
    s11 += dy * dy; s12 += dy * dz; s22 += dz * dz;
  }
#pragma unroll
  for (int m = 1; m < 64; m <<= 1) {
    s0 += __shfl_xor(s0, m, 64);  s1 += __shfl_xor(s1, m, 64);  s2 += __shfl_xor(s2, m, 64);
    s00 += __shfl_xor(s00, m, 64); s01 += __shfl_xor(s01, m, 64); s02 += __shfl_xor(s02, m, 64);
    s11 += __shfl_xor(s11, m, 64); s12 += __shfl_xor(s12, m, 64); s22 += __shfl_xor(s22, m, 64);
  }
  __shared__ float part[4][9];
  const int wave = threadIdx.x >> 6, lane = threadIdx.x & 63;
  if (lane == 0) {
    part[wave][0] = s0;  part[wave][1] = s1;  part[wave][2] = s2;
    part[wave][3] = s00; part[wave][4] = s01; part[wave][5] = s02;
    part[wave][6] = s11; part[wave][7] = s12; part[wave][8] = s22;
  }
  __syncthreads();
  if (threadIdx.x < 9) {
    const float acc = part[0][threadIdx.x] + part[1][threadIdx.x] +
                      part[2][threadIdx.x] + part[3][threadIdx.x];
    atomicAdd(&stats[threadIdx.x], acc);
  }
}

// ---------------- fold BN(+gamma,beta) into effective Wp1/bp1 ----------------
__global__ void finalize_kernel(
    const float* __restrict__ stats,
    const float* __restrict__ Wp1, const float* __restrict__ bp1,
    const float* __restrict__ gamma, const float* __restrict__ beta,
    float* __restrict__ eff) {
  if (threadIdx.x != 0 || blockIdx.x != 0) return;
  const float invM = 1.0f / (float)(N_PTS * NSS);
  const float m0 = stats[0] * invM, m1 = stats[1] * invM, m2 = stats[2] * invM;
  float cov[3][3];
  cov[0][0] = stats[3] * invM - m0 * m0;
  cov[0][1] = cov[1][0] = stats[4] * invM - m0 * m1;
  cov[0][2] = cov[2][0] = stats[5] * invM - m0 * m2;
  cov[1][1] = stats[6] * invM - m1 * m1;
  cov[1][2] = cov[2][1] = stats[7] * invM - m1 * m2;
  cov[2][2] = stats[8] * invM - m2 * m2;
  const float mean[3] = {m0, m1, m2};
  for (int t = 0; t < 3; ++t) {
    const float w[3] = {Wp1[0 * 3 + t], Wp1[1 * 3 + t], Wp1[2 * 3 + t]};
    const float mh = w[0] * mean[0] + w[1] * mean[1] + w[2] * mean[2] + bp1[t];
    float var = 0.f;
    for (int d = 0; d < 3; ++d)
      for (int e = 0; e < 3; ++e) var += w[d] * w[e] * cov[d][e];
    const float scale = gamma[t] * rsqrtf(var + 1e-5f);
    eff[0 * 3 + t] = w[0] * scale;
    eff[1 * 3 + t] = w[1] * scale;
    eff[2 * 3 + t] = w[2] * scale;
    eff[9 + t] = (bp1[t] - mh) * scale + beta[t];
  }
}

// merge two lane-distributed accumulators over xor `bit`:
// lanes with (lane&bit)==0 end with a summed over {l, l^bit}; others get b.
__device__ __forceinline__ float merge2(float a, float b, int bit, int lane) {
  const bool hi = (lane & bit) != 0;
  const float keep = hi ? b : a;
  const float send = hi ? a : b;
  return keep + __shfl_xor(send, bit, 64);
}

__device__ __forceinline__ float dot4(float4 a, float4 b) {
  return fmaf(a.x, b.x, fmaf(a.y, b.y, fmaf(a.z, b.z, a.w * b.w)));
}

// ---------------- main attention: one wave per point ----------------
// lane l: g = l>>4, m = l&15 (channel group of 4). Neighbor assignment sigma(l)=4*(l&3)+g.
__global__ __launch_bounds__(256) void attn_kernel(
    const float* __restrict__ p, const int* __restrict__ idx,
    const float* __restrict__ xq, const float* __restrict__ kv,
    const float* __restrict__ eff, const float* __restrict__ Wp2, const float* __restrict__ bp2,
    float* __restrict__ out) {
  const int lane = threadIdx.x & 63;
  const int n = (blockIdx.x * blockDim.x + threadIdx.x) >> 6;
  const int g = lane >> 4, m = lane & 15;
  const int sig = ((lane & 3) << 2) | g;

  // per-lane channel-group data
  const float4 q4 = ((const float4*)xq)[n * 16 + m];
  const float4 w20 = ((const float4*)Wp2)[0 * 16 + m];
  const float4 w21 = ((const float4*)Wp2)[1 * 16 + m];
  const float4 w22 = ((const float4*)Wp2)[2 * 16 + m];
  const float4 b24 = ((const float4*)bp2)[m];

  // neighbor index for this lane's sigma, plus per-step broadcast copies
  const int jv = idx[n * NSS + sig];
  int jb[4];
#pragma unroll
  for (int i = 0; i < 4; ++i) jb[i] = __shfl(jv, (lane & 48) | i, 64);

  // ---- K phase: gather 16 rows with 4 dwordx4 loads, dot partials ----
  float u[4];
#pragma unroll
  for (int i = 0; i < 4; ++i) {
    const float4 k4 = *(const float4*)(kv + jb[i] * 128 + (m << 2));
    u[i] = dot4(q4, k4);
  }
  // tree-reduce: lane ends with full 64-ch dot of neighbor sigma(l)
  float A = merge2(u[0], u[1], 1, lane);
  float B = merge2(u[2], u[3], 1, lane);
  float S = merge2(A, B, 2, lane);
  S += __shfl_xor(S, 4, 64);
  S += __shfl_xor(S, 8, 64);

  // ---- t = [q.Wp2_0, q.Wp2_1, q.Wp2_2, q.bp2] ----
  float tp0 = dot4(q4, w20), tp1 = dot4(q4, w21), tp2 = dot4(q4, w22), tp3 = dot4(q4, b24);
  float TA = merge2(tp0, tp1, 1, lane);
  float TB = merge2(tp2, tp3, 1, lane);
  float T = merge2(TA, TB, 2, lane);
  T += __shfl_xor(T, 4, 64);
  T += __shfl_xor(T, 8, 64);
  const float t0 = __shfl(T, 0, 64), t1 = __shfl(T, 1, 64);
  const float t2 = __shfl(T, 2, 64), t3 = __shfl(T, 3, 64);

  // ---- h for this lane's neighbor sigma ----
  float e[12];
#pragma unroll
  for (int i = 0; i < 12; ++i) e[i] = eff[i];
  const float pnx = p[n * 3 + 0], pny = p[n * 3 + 1], pnz = p[n * 3 + 2];
  const float dx = p[jv * 3 + 0] - pnx;
  const float dy = p[jv * 3 + 1] - pny;
  const float dz = p[jv * 3 + 2] - pnz;
  const float h0 = fmaxf(fmaf(dx, e[0], fmaf(dy, e[3], fmaf(dz, e[6], e[9]))), 0.f);
  const float h1 = fmaxf(fmaf(dx, e[1], fmaf(dy, e[4], fmaf(dz, e[7], e[10]))), 0.f);
  const float h2 = fmaxf(fmaf(dx, e[2], fmaf(dy, e[5], fmaf(dz, e[8], e[11]))), 0.f);

  // ---- score + softmax over the 16 sigma values (lane bits 0,1,4,5) ----
  const float a = (S + fmaf(h0, t0, fmaf(h1, t1, fmaf(h2, t2, t3)))) * 0.125f;
  float mx = a;
  mx = fmaxf(mx, __shfl_xor(mx, 1, 64));
  mx = fmaxf(mx, __shfl_xor(mx, 2, 64));
  mx = fmaxf(mx, __shfl_xor(mx, 16, 64));
  mx = fmaxf(mx, __shfl_xor(mx, 32, 64));
  const float ex = __expf(a - mx);
  float den = ex;
  den += __shfl_xor(den, 1, 64);
  den += __shfl_xor(den, 2, 64);
  den += __shfl_xor(den, 16, 64);
  den += __shfl_xor(den, 32, 64);
  const float w = ex / den;

  // ---- H = sum_s w_s * h_s ----
  float H0 = w * h0, H1 = w * h1, H2 = w * h2;
  H0 += __shfl_xor(H0, 1, 64); H1 += __shfl_xor(H1, 1, 64); H2 += __shfl_xor(H2, 1, 64);
  H0 += __shfl_xor(H0, 2, 64); H1 += __shfl_xor(H1, 2, 64); H2 += __shfl_xor(H2, 2, 64);
  H0 += __shfl_xor(H0, 16, 64); H1 += __shfl_xor(H1, 16, 64); H2 += __shfl_xor(H2, 16, 64);
  H0 += __shfl_xor(H0, 32, 64); H1 += __shfl_xor(H1, 32, 64); H2 += __shfl_xor(H2, 32, 64);

  // ---- V phase: weighted sum ----
  float o0 = 0, o1 = 0, o2 = 0, o3 = 0;
#pragma unroll
  for (int i = 0; i < 4; ++i) {
    const float wb = __shfl(w, (lane & 48) | i, 64);
    const float4 v4 = *(const float4*)(kv + jb[i] * 128 + 64 + (m << 2));
    o0 = fmaf(wb, v4.x, o0); o1 = fmaf(wb, v4.y, o1);
    o2 = fmaf(wb, v4.z, o2); o3 = fmaf(wb, v4.w, o3);
  }
  // reduce partial row-sums over g (bits 4,5)
  o0 += __shfl_xor(o0, 16, 64); o1 += __shfl_xor(o1, 16, 64);
  o2 += __shfl_xor(o2, 16, 64); o3 += __shfl_xor(o3, 16, 64);
  o0 += __shfl_xor(o0, 32, 64); o1 += __shfl_xor(o1, 32, 64);
  o2 += __shfl_xor(o2, 32, 64); o3 += __shfl_xor(o3, 32, 64);
  // add positional-embedding correction + bias
  o0 += fmaf(H0, w20.x, fmaf(H1, w21.x, H2 * w22.x)) + b24.x;
  o1 += fmaf(H0, w20.y, fmaf(H1, w21.y, H2 * w22.y)) + b24.y;
  o2 += fmaf(H0, w20.z, fmaf(H1, w21.z, H2 * w22.z)) + b24.z;
  o3 += fmaf(H0, w20.w, fmaf(H1, w21.w, H2 * w22.w)) + b24.w;
  if (lane < 16) {
    float4 o = {o0, o1, o2, o3};
    ((float4*)out)[n * 16 + m] = o;
  }
}

extern "C" void kernel_launch(void* const* d_in, const int* in_sizes, int n_in,
                              void* d_out, int out_size, void* d_ws, size_t ws_size,
                              hipStream_t stream) {
  const float* p     = (const float*)d_in[0];
  const float* x     = (const float*)d_in[1];
  const int*   idx   = (const int*)d_in[2];
  const float* Wq    = (const float*)d_in[3];
  const float* bq    = (const float*)d_in[4];
  const float* Wk    = (const float*)d_in[5];
  const float* bk    = (const float*)d_in[6];
  const float* Wv    = (const float*)d_in[7];
  const float* bv    = (const float*)d_in[8];
  const float* Wp1   = (const float*)d_in[9];
  const float* bp1   = (const float*)d_in[10];
  const float* gamma = (const float*)d_in[11];
  const float* beta  = (const float*)d_in[12];
  const float* Wp2   = (const float*)d_in[13];
  const float* bp2   = (const float*)d_in[14];
  float* out = (float*)d_out;

  float* ws_f  = (float*)d_ws;
  float* stats = ws_f;        // 9 floats (zeroed below)
  float* eff   = ws_f + 16;   // 12 floats
  float* xq    = ws_f + 1024; // N*64
  float* kv    = xq + N_PTS * C; // N*128 interleaved k|v

  hipMemsetAsync(stats, 0, 9 * sizeof(float), stream);
  qkv_kernel<<<N_PTS / 64, 256, 0, stream>>>(x, Wq, bq, Wk, bk, Wv, bv, xq, kv);
  stats_kernel<<<1024, 256, 0, stream>>>(p, idx, stats);
  finalize_kernel<<<1, 64, 0, stream>>>(stats, Wp1, bp1, gamma, beta, eff);
  attn_kernel<<<N_PTS / 4, 256, 0, stream>>>(p, idx, xq, kv, eff, Wp2, bp2, out);
}

// Round 3
// 183.409 us; speedup vs baseline: 1.6460x; 1.2281x over previous
//
#include <hip/hip_runtime.h>

#define N_PTS 65536
#define NSS 16
#define C 64

typedef __attribute__((ext_vector_type(8))) short short8;
typedef __attribute__((ext_vector_type(4))) float f32x4;

__device__ __forceinline__ unsigned short f2bf(float v) {
  unsigned int u = __float_as_uint(v);
  u += 0x7fffu + ((u >> 16) & 1u);  // RNE
  return (unsigned short)(u >> 16);
}
__device__ __forceinline__ float bflo(unsigned int u) { return __uint_as_float(u << 16); }
__device__ __forceinline__ float bfhi(unsigned int u) { return __uint_as_float(u & 0xffff0000u); }

// ---------------- init: zero stats + build transposed bf16 weight table wt[n_g][k] ----------------
__global__ void init_kernel(const float* __restrict__ Wq, const float* __restrict__ Wk,
                            const float* __restrict__ Wv, float* __restrict__ stats,
                            unsigned short* __restrict__ wt) {
  const int t = blockIdx.x * 256 + threadIdx.x;
  if (t < 9) stats[t] = 0.f;
  if (t < 192 * 64) {
    const int k = t / 192, ng = t % 192;       // read-coalesced over ng
    const int mat = ng >> 6, n = ng & 63;
    const float* W = mat == 0 ? Wq : (mat == 1 ? Wk : Wv);
    wt[ng * 64 + k] = f2bf(W[k * 64 + n]);
  }
}

// ---------------- QKV via MFMA (bf16 in, fp32 acc) + fused p_r moment stats ----------------
// xq[N][64] fp32; kv[N][128] bf16 (K row | V row)
__global__ __launch_bounds__(256) void qkv_kernel(
    const float* __restrict__ x, const unsigned short* __restrict__ wt,
    const float* __restrict__ bq, const float* __restrict__ bk, const float* __restrict__ bv,
    const float* __restrict__ p, const int* __restrict__ idx,
    float* __restrict__ xq, unsigned short* __restrict__ kv, float* __restrict__ stats) {
  __shared__ unsigned short xs[64][72];  // 9.2 KB, pitch 72 keeps b128 16B-aligned
  const int t = threadIdx.x;
  const int p0 = blockIdx.x * 64;
  const float4* x4 = (const float4*)x;
#pragma unroll
  for (int j = 0; j < 4; ++j) {
    const int id = j * 256 + t;
    const int row = id >> 4, cg = id & 15;
    const float4 v = x4[(p0 + row) * 16 + cg];
    ushort4 h4;
    h4.x = f2bf(v.x); h4.y = f2bf(v.y); h4.z = f2bf(v.z); h4.w = f2bf(v.w);
    *(ushort4*)&xs[row][cg * 4] = h4;
  }
  __syncthreads();

  const int lane = t & 63, wave = t >> 6;
  const int quad = lane >> 4, lr = lane & 15;
  const int mrow = wave * 16 + lr;
  // A-frag: lane holds A[m=lane&15][k=quad*8+j]
  const short8 a0 = *(const short8*)&xs[mrow][quad * 8];
  const short8 a1 = *(const short8*)&xs[mrow][quad * 8 + 32];
#pragma unroll
  for (int nt = 0; nt < 12; ++nt) {
    const unsigned short* bpr = wt + (nt * 16 + lr) * 64 + quad * 8;  // B[n=lane&15][k]
    const short8 b0 = *(const short8*)bpr;
    const short8 b1 = *(const short8*)(bpr + 32);
    f32x4 acc = {0.f, 0.f, 0.f, 0.f};
    acc = __builtin_amdgcn_mfma_f32_16x16x32_bf16(a0, b0, acc, 0, 0, 0);
    acc = __builtin_amdgcn_mfma_f32_16x16x32_bf16(a1, b1, acc, 0, 0, 0);
    const int mat = nt >> 2;
    const int c = (nt & 3) * 16 + lr;  // D: col=lane&15
    const float bias = (mat == 0 ? bq : (mat == 1 ? bk : bv))[c];
#pragma unroll
    for (int r = 0; r < 4; ++r) {  // D: row=quad*4+reg
      const int pt = p0 + wave * 16 + quad * 4 + r;
      const float val = acc[r] + bias;
      if (mat == 0) xq[pt * 64 + c] = val;
      else kv[pt * 128 + (mat == 2 ? 64 : 0) + c] = f2bf(val);
    }
  }

  // ---- fused stats: moments of p_r ----
  const int tid = blockIdx.x * 256 + t;
  float s0 = 0, s1 = 0, s2 = 0, s00 = 0, s01 = 0, s02 = 0, s11 = 0, s12 = 0, s22 = 0;
  for (int s = tid; s < N_PTS * NSS; s += 262144) {
    const int n = s >> 4;
    const int j = idx[s];
    const float dx = p[j * 3 + 0] - p[n * 3 + 0];
    const float dy = p[j * 3 + 1] - p[n * 3 + 1];
    const float dz = p[j * 3 + 2] - p[n * 3 + 2];
    s0 += dx; s1 += dy; s2 += dz;
    s00 += dx * dx; s01 += dx * dy; s02 += dx * dz;
    s11 += dy * dy; s12 += dy * dz; s22 += dz * dz;
  }
#pragma unroll
  for (int m = 1; m < 64; m <<= 1) {
    s0 += __shfl_xor(s0, m, 64);  s1 += __shfl_xor(s1, m, 64);  s2 += __shfl_xor(s2, m, 64);
    s00 += __shfl_xor(s00, m, 64); s01 += __shfl_xor(s01, m, 64); s02 += __shfl_xor(s02, m, 64);
    s11 += __shfl_xor(s11, m, 64); s12 += __shfl_xor(s12, m, 64); s22 += __shfl_xor(s22, m, 64);
  }
  __shared__ float part[4][9];
  if (lane == 0) {
    part[wave][0] = s0;  part[wave][1] = s1;  part[wave][2] = s2;
    part[wave][3] = s00; part[wave][4] = s01; part[wave][5] = s02;
    part[wave][6] = s11; part[wave][7] = s12; part[wave][8] = s22;
  }
  __syncthreads();
  if (t < 9) {
    atomicAdd(&stats[t], part[0][t] + part[1][t] + part[2][t] + part[3][t]);
  }
}

// ---------------- cross-lane helpers ----------------
__device__ __forceinline__ float merge2(float a, float b, int bit, int lane) {
  const bool hi = (lane & bit) != 0;
  const float keep = hi ? b : a;
  const float send = hi ? a : b;
  return keep + __shfl_xor(send, bit, 64);
}
template <int CTRL>
__device__ __forceinline__ float dppmv(float x) {
  return __int_as_float(__builtin_amdgcn_update_dpp(
      __float_as_int(x), __float_as_int(x), CTRL, 0xF, 0xF, true));
}
__device__ __forceinline__ float red16_add(float x) {  // sum over lane bits 0..3
  x += dppmv<0xB1>(x);             // xor 1 (quad_perm, VALU pipe)
  x += dppmv<0x4E>(x);             // xor 2
  x += __shfl_xor(x, 4, 64);
  x += __shfl_xor(x, 8, 64);
  return x;
}
__device__ __forceinline__ float red16_max(float x) {
  x = fmaxf(x, dppmv<0xB1>(x));
  x = fmaxf(x, dppmv<0x4E>(x));
  x = fmaxf(x, __shfl_xor(x, 4, 64));
  x = fmaxf(x, __shfl_xor(x, 8, 64));
  return x;
}
__device__ __forceinline__ float red8_add(float x) {  // sum over lane bits 0..2
  x += dppmv<0xB1>(x);
  x += dppmv<0x4E>(x);
  x += __shfl_xor(x, 4, 64);
  return x;
}
__device__ __forceinline__ float dot8q(const float4 a, const float4 b, const uint4 r) {
  float s = a.x * bflo(r.x);
  s = fmaf(a.y, bfhi(r.x), s);
  s = fmaf(a.z, bflo(r.y), s);
  s = fmaf(a.w, bfhi(r.y), s);
  s = fmaf(b.x, bflo(r.z), s);
  s = fmaf(b.y, bfhi(r.z), s);
  s = fmaf(b.z, bflo(r.w), s);
  s = fmaf(b.w, bfhi(r.w), s);
  return s;
}
__device__ __forceinline__ float dot8f(const float4 a, const float4 b,
                                       const float4 c, const float4 d) {
  float s = a.x * c.x;
  s = fmaf(a.y, c.y, s); s = fmaf(a.z, c.z, s); s = fmaf(a.w, c.w, s);
  s = fmaf(b.x, d.x, s); s = fmaf(b.y, d.y, s); s = fmaf(b.z, d.z, s); s = fmaf(b.w, d.w, s);
  return s;
}

// ---------------- attention: one wave per point; sigma = lane&15, chan-slice = lane>>3 ----------------
__global__ __launch_bounds__(256, 4) void attn_kernel(
    const float* __restrict__ p, const int* __restrict__ idx,
    const float* __restrict__ xq, const unsigned short* __restrict__ kv,
    const float* __restrict__ stats,
    const float* __restrict__ Wp1, const float* __restrict__ bp1,
    const float* __restrict__ gamma, const float* __restrict__ beta,
    const float* __restrict__ Wp2, const float* __restrict__ bp2,
    float* __restrict__ out) {
  const int lane = threadIdx.x & 63;
  const int n = (blockIdx.x * blockDim.x + threadIdx.x) >> 6;
  const int slice = lane >> 3;  // channel slice (8 chans)
  const int rlo = lane & 7;

  const int jall = idx[n * NSS + (lane & 15)];  // own sigma's neighbor
  const int jb0 = __shfl(jall, rlo, 64);        // row rlo
  const int jb1 = __shfl(jall, rlo | 8, 64);    // row rlo+8

  // issue all gathers up front (7 in flight)
  const uint4 kr0 = *(const uint4*)(kv + (size_t)jb0 * 128 + slice * 8);
  const uint4 kr1 = *(const uint4*)(kv + (size_t)jb1 * 128 + slice * 8);
  const uint4 vr0 = *(const uint4*)(kv + (size_t)jb0 * 128 + 64 + slice * 8);
  const uint4 vr1 = *(const uint4*)(kv + (size_t)jb1 * 128 + 64 + slice * 8);
  const float pjx = p[jall * 3 + 0], pjy = p[jall * 3 + 1], pjz = p[jall * 3 + 2];
  const float pnx = p[n * 3 + 0], pny = p[n * 3 + 1], pnz = p[n * 3 + 2];

  const float4* xq4 = (const float4*)xq;
  const float4 qa = xq4[n * 16 + slice * 2], qb = xq4[n * 16 + slice * 2 + 1];
  const float4* w24 = (const float4*)Wp2;
  const float4 w20a = w24[slice * 2],      w20b = w24[slice * 2 + 1];
  const float4 w21a = w24[16 + slice * 2], w21b = w24[16 + slice * 2 + 1];
  const float4 w22a = w24[32 + slice * 2], w22b = w24[32 + slice * 2 + 1];
  const float4* bp24 = (const float4*)bp2;
  const float4 b2a = bp24[slice * 2], b2b = bp24[slice * 2 + 1];

  // inline finalize: fold BN into eff (wave-uniform scalar work)
  const float invM = 1.0f / (float)(N_PTS * NSS);
  const float m0 = stats[0] * invM, m1 = stats[1] * invM, m2 = stats[2] * invM;
  const float cv00 = stats[3] * invM - m0 * m0, cv01 = stats[4] * invM - m0 * m1;
  const float cv02 = stats[5] * invM - m0 * m2, cv11 = stats[6] * invM - m1 * m1;
  const float cv12 = stats[7] * invM - m1 * m2, cv22 = stats[8] * invM - m2 * m2;
  float e[12];
#pragma unroll
  for (int tt = 0; tt < 3; ++tt) {
    const float w0 = Wp1[0 * 3 + tt], w1 = Wp1[1 * 3 + tt], w2 = Wp1[2 * 3 + tt];
    const float mh = w0 * m0 + w1 * m1 + w2 * m2 + bp1[tt];
    const float var = w0 * w0 * cv00 + w1 * w1 * cv11 + w2 * w2 * cv22 +
                      2.f * (w0 * w1 * cv01 + w0 * w2 * cv02 + w1 * w2 * cv12);
    const float sc = gamma[tt] * rsqrtf(var + 1e-5f);
    e[tt] = w0 * sc; e[3 + tt] = w1 * sc; e[6 + tt] = w2 * sc;
    e[9 + tt] = (bp1[tt] - mh) * sc + beta[tt];
  }

  // K phase: lane ends with full 64-ch dot for sigma = lane&15
  float S = merge2(dot8q(qa, qb, kr0), dot8q(qa, qb, kr1), 8, lane);
  S += __shfl_xor(S, 16, 64);
  S += __shfl_xor(S, 32, 64);

  // T = [q.Wp2_0, q.Wp2_1, q.Wp2_2, q.bp2]
  const float tp0 = dot8f(qa, qb, w20a, w20b);
  const float tp1 = dot8f(qa, qb, w21a, w21b);
  const float tp2 = dot8f(qa, qb, w22a, w22b);
  const float tp3 = dot8f(qa, qb, b2a, b2b);
  float T = merge2(merge2(tp0, tp1, 8, lane), merge2(tp2, tp3, 8, lane), 16, lane);
  T += __shfl_xor(T, 32, 64);
  const float t0 = __shfl(T, 0, 64), t1 = __shfl(T, 8, 64);
  const float t2 = __shfl(T, 16, 64), t3 = __shfl(T, 24, 64);

  // h for own sigma
  const float dx = pjx - pnx, dy = pjy - pny, dz = pjz - pnz;
  const float h0 = fmaxf(fmaf(dx, e[0], fmaf(dy, e[3], fmaf(dz, e[6], e[9]))), 0.f);
  const float h1 = fmaxf(fmaf(dx, e[1], fmaf(dy, e[4], fmaf(dz, e[7], e[10]))), 0.f);
  const float h2 = fmaxf(fmaf(dx, e[2], fmaf(dy, e[5], fmaf(dz, e[8], e[11]))), 0.f);

  // score + softmax over sigma (lane bits 0..3)
  const float a = (S + fmaf(h0, t0, fmaf(h1, t1, fmaf(h2, t2, t3)))) * 0.125f;
  const float mx = red16_max(a);
  const float ex = __expf(a - mx);
  const float den = red16_add(ex);
  const float w = ex / den;

  // H = sum_s w_s h_s
  const float H0 = red16_add(w * h0);
  const float H1 = red16_add(w * h1);
  const float H2 = red16_add(w * h2);

  // V phase
  const float wb0 = __shfl(w, rlo, 64);
  const float wb1 = __shfl(w, rlo | 8, 64);
  const unsigned int v0c[4] = {vr0.x, vr0.y, vr0.z, vr0.w};
  const unsigned int v1c[4] = {vr1.x, vr1.y, vr1.z, vr1.w};
  float o[8];
#pragma unroll
  for (int q2 = 0; q2 < 4; ++q2) {
    o[2 * q2]     = fmaf(wb0, bflo(v0c[q2]), wb1 * bflo(v1c[q2]));
    o[2 * q2 + 1] = fmaf(wb0, bfhi(v0c[q2]), wb1 * bfhi(v1c[q2]));
  }
#pragma unroll
  for (int j = 0; j < 8; ++j) o[j] = red8_add(o[j]);

  const float w20f[8] = {w20a.x, w20a.y, w20a.z, w20a.w, w20b.x, w20b.y, w20b.z, w20b.w};
  const float w21f[8] = {w21a.x, w21a.y, w21a.z, w21a.w, w21b.x, w21b.y, w21b.z, w21b.w};
  const float w22f[8] = {w22a.x, w22a.y, w22a.z, w22a.w, w22b.x, w22b.y, w22b.z, w22b.w};
  const float b2f[8]  = {b2a.x, b2a.y, b2a.z, b2a.w, b2b.x, b2b.y, b2b.z, b2b.w};
#pragma unroll
  for (int j = 0; j < 8; ++j)
    o[j] += fmaf(H0, w20f[j], fmaf(H1, w21f[j], fmaf(H2, w22f[j], b2f[j])));

  if (rlo == 0) {
    float4 oa = {o[0], o[1], o[2], o[3]};
    float4 ob = {o[4], o[5], o[6], o[7]};
    float4* o4 = (float4*)out;
    o4[n * 16 + slice * 2] = oa;
    o4[n * 16 + slice * 2 + 1] = ob;
  }
}

extern "C" void kernel_launch(void* const* d_in, const int* in_sizes, int n_in,
                              void* d_out, int out_size, void* d_ws, size_t ws_size,
                              hipStream_t stream) {
  const float* p     = (const float*)d_in[0];
  const float* x     = (const float*)d_in[1];
  const int*   idx   = (const int*)d_in[2];
  const float* Wq    = (const float*)d_in[3];
  const float* bq    = (const float*)d_in[4];
  const float* Wk    = (const float*)d_in[5];
  const float* bk    = (const float*)d_in[6];
  const float* Wv    = (const float*)d_in[7];
  const float* bv    = (const float*)d_in[8];
  const float* Wp1   = (const float*)d_in[9];
  const float* bp1   = (const float*)d_in[10];
  const float* gamma = (const float*)d_in[11];
  const float* beta  = (const float*)d_in[12];
  const float* Wp2   = (const float*)d_in[13];
  const float* bp2   = (const float*)d_in[14];
  float* out = (float*)d_out;

  float* stats = (float*)d_ws;                                        // 9 floats
  unsigned short* wt = (unsigned short*)((char*)d_ws + 256);          // 24.6 KB
  float* xq = (float*)((char*)d_ws + 32768);                          // 16.8 MB
  unsigned short* kv = (unsigned short*)((char*)d_ws + 32768 + (size_t)N_PTS * C * 4);  // 16.8 MB

  init_kernel<<<48, 256, 0, stream>>>(Wq, Wk, Wv, stats, wt);
  qkv_kernel<<<N_PTS / 64, 256, 0, stream>>>(x, wt, bq, bk, bv, p, idx, xq, kv, stats);
  attn_kernel<<<N_PTS / 4, 256, 0, stream>>>(p, idx, xq, kv, stats, Wp1, bp1, gamma, beta,
                                             Wp2, bp2, out);
}